// Round 3
// baseline (100.823 us; speedup 1.0000x reference)
//
#include <hip/hip_runtime.h>

#define Bsz 128
#define Csz 1024
#define Nsz 512
#define NCsz 1024
#define CAP 64    // max body literals per clause per sign; E=10.2, P(>64)~0
#define HCAP 32   // max clauses per (head atom, sign); E=1, max ~8

// ---------------- Kernel 1: gather mT + clause structure extraction ----------------
// blocks 0..255  : gather mT[n][b] = preds[b][atoms[n]]  (65536 threads)
// blocks 256..511: wave-per-clause: float4 scan of body/head rows -> literal lists + head
__global__ __launch_bounds__(256) void k_pre(
    const float* __restrict__ preds,
    const float* __restrict__ pos_head, const float* __restrict__ neg_head,
    const float* __restrict__ pos_body, const float* __restrict__ neg_body,
    const int* __restrict__ atoms,
    float* __restrict__ mT,
    int* __restrict__ pos_list, int* __restrict__ neg_list,
    int* __restrict__ pos_cnt, int* __restrict__ neg_cnt,
    int* __restrict__ head_n, int* __restrict__ head_sign)
{
    int blk = blockIdx.x;
    if (blk < 256) {
        int g = blk * 256 + threadIdx.x;          // [0, 65536)
        int b = g >> 9, n = g & 511;              // n fast -> sorted-atom coalesced reads
        mT[n * Bsz + b] = preds[b * NCsz + atoms[n]];
    } else {
        __shared__ int cnts[4][2];
        int wave = threadIdx.x >> 6, lane = threadIdx.x & 63;
        int c = (blk - 256) * 4 + wave;           // 256 blocks * 4 waves = 1024 clauses
        if (lane == 0) { cnts[wave][0] = 0; cnts[wave][1] = 0; }
        // per-wave LDS counters + wave-ordered instruction stream: no barrier needed
        const float4* pb4 = (const float4*)(pos_body + c * Nsz);
        const float4* nb4 = (const float4*)(neg_body + c * Nsz);
        const float4* ph4 = (const float4*)(pos_head + c * Nsz);
        const float4* nh4 = (const float4*)(neg_head + c * Nsz);
        for (int k = 0; k < 2; k++) {
            int q = k * 64 + lane;                // float4 index, n0 = 4*q
            float4 p = pb4[q];
            float4 nb = nb4[q];
            float4 ph = ph4[q];
            float4 nh = nh4[q];
            int n0 = q * 4;
            if (p.x != 0.f) { int s = atomicAdd(&cnts[wave][0], 1); if (s < CAP) pos_list[c * CAP + s] = n0; }
            if (p.y != 0.f) { int s = atomicAdd(&cnts[wave][0], 1); if (s < CAP) pos_list[c * CAP + s] = n0 + 1; }
            if (p.z != 0.f) { int s = atomicAdd(&cnts[wave][0], 1); if (s < CAP) pos_list[c * CAP + s] = n0 + 2; }
            if (p.w != 0.f) { int s = atomicAdd(&cnts[wave][0], 1); if (s < CAP) pos_list[c * CAP + s] = n0 + 3; }
            if (nb.x != 0.f) { int s = atomicAdd(&cnts[wave][1], 1); if (s < CAP) neg_list[c * CAP + s] = n0; }
            if (nb.y != 0.f) { int s = atomicAdd(&cnts[wave][1], 1); if (s < CAP) neg_list[c * CAP + s] = n0 + 1; }
            if (nb.z != 0.f) { int s = atomicAdd(&cnts[wave][1], 1); if (s < CAP) neg_list[c * CAP + s] = n0 + 2; }
            if (nb.w != 0.f) { int s = atomicAdd(&cnts[wave][1], 1); if (s < CAP) neg_list[c * CAP + s] = n0 + 3; }
            if (ph.x != 0.f) { head_n[c] = n0;     head_sign[c] = 1; }
            if (ph.y != 0.f) { head_n[c] = n0 + 1; head_sign[c] = 1; }
            if (ph.z != 0.f) { head_n[c] = n0 + 2; head_sign[c] = 1; }
            if (ph.w != 0.f) { head_n[c] = n0 + 3; head_sign[c] = 1; }
            if (nh.x != 0.f) { head_n[c] = n0;     head_sign[c] = 0; }
            if (nh.y != 0.f) { head_n[c] = n0 + 1; head_sign[c] = 0; }
            if (nh.z != 0.f) { head_n[c] = n0 + 2; head_sign[c] = 0; }
            if (nh.w != 0.f) { head_n[c] = n0 + 3; head_sign[c] = 0; }
        }
        if (lane == 0) {
            pos_cnt[c] = min(cnts[wave][0], CAP);
            neg_cnt[c] = min(cnts[wave][1], CAP);
        }
    }
}

// ---------------- Kernel 2: per-atom gather-reduce + clamp + full output write ----------
// blocks 0..511   : atom block n — find clauses with head n (scan head_n, L2-hot),
//                   reduce body_min over them in registers, clamp, write atom column.
// blocks 512..1023: pass-through copy of non-atom columns (binary-search predicate).
__global__ __launch_bounds__(128) void k_solve(
    const float* __restrict__ preds,
    const float* __restrict__ mT,
    const int* __restrict__ pos_list, const int* __restrict__ neg_list,
    const int* __restrict__ pos_cnt, const int* __restrict__ neg_cnt,
    const int* __restrict__ head_n, const int* __restrict__ head_sign,
    const int* __restrict__ atoms,
    float* __restrict__ out)
{
    int blk = blockIdx.x, tid = threadIdx.x;
    if (blk < Nsz) {
        __shared__ int pc_list[HCAP], nc_list[HCAP];
        __shared__ int np, nn;
        if (tid == 0) { np = 0; nn = 0; }
        __syncthreads();
        for (int c = tid; c < Csz; c += 128) {
            if (head_n[c] == blk) {
                if (head_sign[c]) { int s = atomicAdd(&np, 1); if (s < HCAP) pc_list[s] = c; }
                else              { int s = atomicAdd(&nn, 1); if (s < HCAP) nc_list[s] = c; }
            }
        }
        __syncthreads();
        int npc = min(np, HCAP), nnc = min(nn, HCAP);
        float lbv = 0.f, ubacc = 0.f;
        for (int i = 0; i < npc; i++) {
            int c = pc_list[i];
            float acc = 0.f;
            int pcn = pos_cnt[c], ncn = neg_cnt[c];
            const int* pl = pos_list + c * CAP;
            const int* nl = neg_list + c * CAP;
            for (int e = 0; e < pcn; e++) acc = fmaxf(acc, 1.f - mT[pl[e] * Bsz + tid]);
            for (int e = 0; e < ncn; e++) acc = fmaxf(acc, mT[nl[e] * Bsz + tid]);
            lbv = fmaxf(lbv, 1.f - acc);          // body_min of clause c, batch tid
        }
        for (int i = 0; i < nnc; i++) {
            int c = nc_list[i];
            float acc = 0.f;
            int pcn = pos_cnt[c], ncn = neg_cnt[c];
            const int* pl = pos_list + c * CAP;
            const int* nl = neg_list + c * CAP;
            for (int e = 0; e < pcn; e++) acc = fmaxf(acc, 1.f - mT[pl[e] * Bsz + tid]);
            for (int e = 0; e < ncn; e++) acc = fmaxf(acc, mT[nl[e] * Bsz + tid]);
            ubacc = fmaxf(ubacc, 1.f - acc);
        }
        float m  = mT[blk * Bsz + tid];
        float ub = 1.f - ubacc;                    // 1 if no neg-head clause
        float lo = fminf(lbv, ub), hi = fmaxf(lbv, ub);
        out[tid * NCsz + atoms[blk]] = fmaxf(lo, fminf(hi, m));
    } else {
        __shared__ int la[Nsz];
        for (int i = tid; i < Nsz; i += 128) la[i] = atoms[i];
        __syncthreads();
        int t = (blk - Nsz) * 128 + tid;          // [0, 65536)
        int b = t >> 10, j = t & 1023;            // j fast -> coalesced
        // lower_bound on sorted atoms (9 iterations, uniform trip count)
        int lo = 0, hi = Nsz;
        while (lo < hi) { int mid = (lo + hi) >> 1; if (la[mid] < j) lo = mid + 1; else hi = mid; }
        bool isatom = (lo < Nsz) && (la[lo] == j);
        if (!isatom) {
            out[b * NCsz + j]        = preds[b * NCsz + j];
            out[(b + 64) * NCsz + j] = preds[(b + 64) * NCsz + j];
        }
    }
}

extern "C" void kernel_launch(void* const* d_in, const int* in_sizes, int n_in,
                              void* d_out, int out_size, void* d_ws, size_t ws_size,
                              hipStream_t stream)
{
    const float* preds    = (const float*)d_in[0];
    const float* pos_head = (const float*)d_in[1];
    const float* neg_head = (const float*)d_in[2];
    const float* pos_body = (const float*)d_in[3];
    const float* neg_body = (const float*)d_in[4];
    const int*   atoms    = (const int*)d_in[5];
    float* out = (float*)d_out;

    char* ws = (char*)d_ws;
    float* mT        = (float*)(ws);                 // 65536 f32 (mT[n][b])
    int*   pos_list  = (int*)(ws + 65536u  * 4);     // C*CAP
    int*   neg_list  = (int*)(ws + 131072u * 4);     // C*CAP
    int*   pos_cnt   = (int*)(ws + 196608u * 4);     // C
    int*   neg_cnt   = pos_cnt + Csz;
    int*   head_n    = neg_cnt + Csz;
    int*   head_sign = head_n + Csz;                 // ~0.78 MB total

    k_pre<<<512, 256, 0, stream>>>(preds, pos_head, neg_head, pos_body, neg_body, atoms,
                                   mT, pos_list, neg_list, pos_cnt, neg_cnt,
                                   head_n, head_sign);

    k_solve<<<Nsz + 512, 128, 0, stream>>>(preds, mT, pos_list, neg_list,
                                           pos_cnt, neg_cnt, head_n, head_sign,
                                           atoms, out);
}

// Round 4
// 78.061 us; speedup vs baseline: 1.2916x; 1.2916x over previous
//
#include <hip/hip_runtime.h>

#define Bsz 128
#define Csz 1024
#define Nsz 512
#define NCsz 1024
#define CAP 64    // max body literals per clause per sign; E=10.2, P(>64)~0

// ---------------- Kernel 1: zero bounds + gather mT + clause structure ----------------
// blocks   0..127: uint4-zero lbmax/ubmax (131072 u32)
// blocks 128..383: gather mT[n][b] = preds[b][atoms[n]]
// blocks 384..639: wave-per-clause float4 scan -> literal lists + head
__global__ __launch_bounds__(256) void k_pre(
    const float* __restrict__ preds,
    const float* __restrict__ pos_head, const float* __restrict__ neg_head,
    const float* __restrict__ pos_body, const float* __restrict__ neg_body,
    const int* __restrict__ atoms,
    float* __restrict__ mT, unsigned* __restrict__ lbmax, unsigned* __restrict__ ubmax,
    int* __restrict__ pos_list, int* __restrict__ neg_list,
    int* __restrict__ pos_cnt, int* __restrict__ neg_cnt,
    int* __restrict__ head_n, int* __restrict__ head_sign)
{
    int blk = blockIdx.x;
    if (blk < 128) {
        int q = blk * 256 + threadIdx.x;          // [0, 32768) uint4s over lbmax||ubmax
        ((uint4*)lbmax)[q] = make_uint4(0u, 0u, 0u, 0u);   // lbmax+ubmax contiguous in ws
    } else if (blk < 384) {
        int g = (blk - 128) * 256 + threadIdx.x;  // [0, 65536)
        int b = g >> 9, n = g & 511;              // n fast -> sorted-atom window reads
        mT[n * Bsz + b] = preds[b * NCsz + atoms[n]];
    } else {
        __shared__ int cnts[4][2];
        int wave = threadIdx.x >> 6, lane = threadIdx.x & 63;
        int c = (blk - 384) * 4 + wave;           // 256 blocks * 4 waves = 1024 clauses
        if (lane == 0) { cnts[wave][0] = 0; cnts[wave][1] = 0; }
        // per-wave LDS counters, wave-ordered stream: no barrier needed
        const float4* pb4 = (const float4*)(pos_body + c * Nsz);
        const float4* nb4 = (const float4*)(neg_body + c * Nsz);
        const float4* ph4 = (const float4*)(pos_head + c * Nsz);
        const float4* nh4 = (const float4*)(neg_head + c * Nsz);
        for (int k = 0; k < 2; k++) {
            int q = k * 64 + lane;                // float4 index, n0 = 4*q
            float4 p  = pb4[q];
            float4 nb = nb4[q];
            float4 ph = ph4[q];
            float4 nh = nh4[q];
            int n0 = q * 4;
            if (p.x != 0.f) { int s = atomicAdd(&cnts[wave][0], 1); if (s < CAP) pos_list[c * CAP + s] = n0; }
            if (p.y != 0.f) { int s = atomicAdd(&cnts[wave][0], 1); if (s < CAP) pos_list[c * CAP + s] = n0 + 1; }
            if (p.z != 0.f) { int s = atomicAdd(&cnts[wave][0], 1); if (s < CAP) pos_list[c * CAP + s] = n0 + 2; }
            if (p.w != 0.f) { int s = atomicAdd(&cnts[wave][0], 1); if (s < CAP) pos_list[c * CAP + s] = n0 + 3; }
            if (nb.x != 0.f) { int s = atomicAdd(&cnts[wave][1], 1); if (s < CAP) neg_list[c * CAP + s] = n0; }
            if (nb.y != 0.f) { int s = atomicAdd(&cnts[wave][1], 1); if (s < CAP) neg_list[c * CAP + s] = n0 + 1; }
            if (nb.z != 0.f) { int s = atomicAdd(&cnts[wave][1], 1); if (s < CAP) neg_list[c * CAP + s] = n0 + 2; }
            if (nb.w != 0.f) { int s = atomicAdd(&cnts[wave][1], 1); if (s < CAP) neg_list[c * CAP + s] = n0 + 3; }
            if (ph.x != 0.f) { head_n[c] = n0;     head_sign[c] = 1; }
            if (ph.y != 0.f) { head_n[c] = n0 + 1; head_sign[c] = 1; }
            if (ph.z != 0.f) { head_n[c] = n0 + 2; head_sign[c] = 1; }
            if (ph.w != 0.f) { head_n[c] = n0 + 3; head_sign[c] = 1; }
            if (nh.x != 0.f) { head_n[c] = n0;     head_sign[c] = 0; }
            if (nh.y != 0.f) { head_n[c] = n0 + 1; head_sign[c] = 0; }
            if (nh.z != 0.f) { head_n[c] = n0 + 2; head_sign[c] = 0; }
            if (nh.w != 0.f) { head_n[c] = n0 + 3; head_sign[c] = 0; }
        }
        if (lane == 0) {
            pos_cnt[c] = min(cnts[wave][0], CAP);
            neg_cnt[c] = min(cnts[wave][1], CAP);
        }
    }
}

// ---------------- Kernel 2: body_min + scatter-max into bounds ----------------
// One block per clause c, 128 threads = batch b. All reads/atomics b-coalesced.
// body_min in [0,1] (preds uniform [0,1)) -> float bits monotone -> uint atomicMax exact.
__global__ __launch_bounds__(128) void k_body(
    const float* __restrict__ mT,
    const int* __restrict__ pos_list, const int* __restrict__ neg_list,
    const int* __restrict__ pos_cnt, const int* __restrict__ neg_cnt,
    const int* __restrict__ head_n, const int* __restrict__ head_sign,
    unsigned* __restrict__ lbmax, unsigned* __restrict__ ubmax)
{
    int c = blockIdx.x, b = threadIdx.x;
    int pc = pos_cnt[c], ncnt = neg_cnt[c];
    const int* pl = pos_list + c * CAP;
    const int* nl = neg_list + c * CAP;
    float acc = 0.f;
    for (int e = 0; e < pc; e++)   acc = fmaxf(acc, 1.f - mT[pl[e] * Bsz + b]);
    for (int e = 0; e < ncnt; e++) acc = fmaxf(acc, mT[nl[e] * Bsz + b]);
    float bm = 1.f - acc;                          // body_min[b,c] >= 0
    unsigned* dst = head_sign[c] ? lbmax : ubmax;  // pos head -> lb, neg head -> ub
    atomicMax(dst + head_n[c] * Bsz + b, __float_as_uint(bm));
}

// ---------------- Kernel 3: clamp + full output write (atom + pass-through) ----------
// blocks   0..255: atom columns — b-fast coalesced reads of mT/lbmax/ubmax, scatter write
// blocks 256..767: pass-through of non-atom columns (binary-search predicate)
__global__ __launch_bounds__(256) void k_final(
    const float* __restrict__ preds,
    const float* __restrict__ mT,
    const unsigned* __restrict__ lbmax, const unsigned* __restrict__ ubmax,
    const int* __restrict__ atoms, float* __restrict__ out)
{
    int blk = blockIdx.x, tid = threadIdx.x;
    if (blk < 256) {
        int t = blk * 256 + tid;                  // [0, 65536)
        int b = t & 127, n = t >> 7;              // b fast -> coalesced mT/lb/ub reads
        int i = n * Bsz + b;
        float m  = mT[i];
        float lb = __uint_as_float(lbmax[i]);
        float ub = 1.f - __uint_as_float(ubmax[i]);
        float lo = fminf(lb, ub), hi = fmaxf(lb, ub);
        out[b * NCsz + atoms[n]] = fmaxf(lo, fminf(hi, m));
    } else {
        __shared__ int la[Nsz];
        for (int i = tid; i < Nsz; i += 256) la[i] = atoms[i];
        __syncthreads();
        int t = (blk - 256) * 256 + tid;          // [0, 131072)
        int b = t >> 10, j = t & 1023;            // j fast -> coalesced
        int lo = 0, hi = Nsz;                     // lower_bound on sorted atoms
        while (lo < hi) { int mid = (lo + hi) >> 1; if (la[mid] < j) lo = mid + 1; else hi = mid; }
        bool isatom = (lo < Nsz) && (la[lo] == j);
        if (!isatom) out[b * NCsz + j] = preds[b * NCsz + j];
    }
}

extern "C" void kernel_launch(void* const* d_in, const int* in_sizes, int n_in,
                              void* d_out, int out_size, void* d_ws, size_t ws_size,
                              hipStream_t stream)
{
    const float* preds    = (const float*)d_in[0];
    const float* pos_head = (const float*)d_in[1];
    const float* neg_head = (const float*)d_in[2];
    const float* pos_body = (const float*)d_in[3];
    const float* neg_body = (const float*)d_in[4];
    const int*   atoms    = (const int*)d_in[5];
    float* out = (float*)d_out;

    char* ws = (char*)d_ws;
    float*    mT        = (float*)(ws);                       // 65536 f32 (mT[n][b])
    unsigned* lbmax     = (unsigned*)(ws + 65536u  * 4);      // 65536 u32 ([n][b])
    unsigned* ubmax     = (unsigned*)(ws + 131072u * 4);      // 65536 u32 (contiguous after lbmax)
    int*      pos_list  = (int*)(ws + 196608u * 4);           // C*CAP
    int*      neg_list  = (int*)(ws + 262144u * 4);           // C*CAP
    int*      pos_cnt   = (int*)(ws + 327680u * 4);           // C
    int*      neg_cnt   = pos_cnt + Csz;
    int*      head_n    = neg_cnt + Csz;
    int*      head_sign = head_n + Csz;                       // ~1.3 MB total

    k_pre<<<640, 256, 0, stream>>>(preds, pos_head, neg_head, pos_body, neg_body, atoms,
                                   mT, lbmax, ubmax, pos_list, neg_list,
                                   pos_cnt, neg_cnt, head_n, head_sign);

    k_body<<<Csz, Bsz, 0, stream>>>(mT, pos_list, neg_list, pos_cnt, neg_cnt,
                                    head_n, head_sign, lbmax, ubmax);

    k_final<<<768, 256, 0, stream>>>(preds, mT, lbmax, ubmax, atoms, out);
}